// Round 3
// 230.688 us; speedup vs baseline: 1.3639x; 1.3639x over previous
//
#include <hip/hip_runtime.h>
#include <math.h>

#define Bn 8
#define Tn 2048
#define En 1024
#define Hn 128
#define SQRTH 11.313708498984761f

typedef __attribute__((ext_vector_type(8))) short short8;
typedef __attribute__((ext_vector_type(4))) short short4v;
typedef __attribute__((ext_vector_type(4))) float float4v;

#define MFMA16(a, b, c) __builtin_amdgcn_mfma_f32_16x16x32_bf16((a), (b), (c), 0, 0, 0)

static __device__ __forceinline__ unsigned short f2bf(float f) {
    unsigned u = __float_as_uint(f);
    u += 0x7FFFu + ((u >> 16) & 1u);   // RNE
    return (unsigned short)(u >> 16);
}
static __device__ __forceinline__ float bf2f(unsigned short h) {
    return __uint_as_float(((unsigned)h) << 16);
}

// async global->LDS, 16 B per lane. LDS dest is wave-uniform base + lane*16.
static __device__ __forceinline__ void gll16(const unsigned short* g, unsigned short* l) {
    __builtin_amdgcn_global_load_lds(
        (const __attribute__((address_space(1))) unsigned int*)g,
        (__attribute__((address_space(3))) unsigned int*)l, 16, 0, 0);
}

// ---------------------------------------------------------------------------
// SWIZZLE (R8): q/k rows are 128 shorts = 16 blocks of 16 B; block j of row
// t stored at j ^ (t & 15). vtt rows are 32 shorts = 4 blocks; block j of
// row h stored at j ^ ((h>>1) & 3). Swizzle baked into GLOBAL layout; all
// readers adjust.
//
// R9:  split stats/out reductions into <=16-iter chunks (80 blocks x B),
//      fp32 partials into dead xt workspace, combine kernels after.
// R10: rebused double-buffer parity — still failed (inf).
// R11: the double-buffer/prefetch state machine is the repeat-offender bug
//      class; delete it. Single LDS buffer, stage(c) -> barrier -> compute
//      -> barrier. Chunked blocks are short (<=16 iters) and small-LDS
//      (16/29 KB -> ~5 blocks/CU), so inter-block TLP hides the stage
//      latency instead of intra-block prefetch. Also clamp exp arg <= 0
//      (exact for true data; forbids inf from the exp path).
// ---------------------------------------------------------------------------

// ---------------------------------------------------------------------------
// Kernel 0: W (E,H) fp32 -> K-tiled split bf16 wtt[z][ks][128 h][32 k]
// ---------------------------------------------------------------------------
__global__ __launch_bounds__(256) void wtrans_kernel(
    const float* __restrict__ Wq, const float* __restrict__ Wk, const float* __restrict__ Wv,
    unsigned short* __restrict__ wtt_hi, unsigned short* __restrict__ wtt_lo)
{
    int t = blockIdx.x * 256 + threadIdx.x;   // 0..49151
    int kc8 = t & 3;
    int hh = (t >> 2) & 127;
    int ks = (t >> 9) & 31;
    int z = t >> 14;
    const float* W = (z == 0) ? Wq : ((z == 1) ? Wk : Wv);
    short8 h8, l8;
#pragma unroll
    for (int j = 0; j < 8; j++) {
        int e = ks * 32 + kc8 * 8 + j;
        float v = W[(size_t)e * Hn + hh];
        unsigned short hi = f2bf(v);
        h8[j] = (short)hi;
        l8[j] = (short)f2bf(v - bf2f(hi));
    }
    size_t d = (((size_t)z * 32 + ks) * 4096) + (size_t)hh * 32 + kc8 * 8;
    *(short8*)(wtt_hi + d) = h8;
    *(short8*)(wtt_lo + d) = l8;
}

// ---------------------------------------------------------------------------
// Kernel 0b: x fp32 -> K-tiled split bf16 xt[mt][ks][64 r][32 k].
// ---------------------------------------------------------------------------
__global__ __launch_bounds__(256) void xconv_kernel(
    const float* __restrict__ x,
    unsigned short* __restrict__ xt_hi, unsigned short* __restrict__ xt_lo)
{
    int g = blockIdx.x * 256 + threadIdx.x;   // 0..2097151
    int kc8 = g & 3;
    int rr = (g >> 2) & 63;
    int ks = (g >> 8) & 31;
    int mt = g >> 13;
    size_t src = ((size_t)mt * 64 + rr) * En + ks * 32 + kc8 * 8;
    float4v f0 = *(const float4v*)(x + src);
    float4v f1 = *(const float4v*)(x + src + 4);
    short8 h, l;
#pragma unroll
    for (int j = 0; j < 4; j++) {
        unsigned short h0 = f2bf(f0[j]);
        h[j] = (short)h0; l[j] = (short)f2bf(f0[j] - bf2f(h0));
        unsigned short h1 = f2bf(f1[j]);
        h[j + 4] = (short)h1; l[j + 4] = (short)f2bf(f1[j] - bf2f(h1));
    }
    size_t d = (size_t)g * 8;
    *(short8*)(xt_hi + d) = h;
    *(short8*)(xt_lo + d) = l;
}

// ---------------------------------------------------------------------------
// Kernel 1: projections, LDS double-buffered GEMM (unchanged from R8 — this
// kernel's pipeline is harness-verified). q/k written with the 16-B-block
// row swizzle; v written s-chunk-tiled vtt[b][sc][128 h][32 s].
// ---------------------------------------------------------------------------
__global__ __launch_bounds__(256) void proj_kernel(
    const unsigned short* __restrict__ xt_hi, const unsigned short* __restrict__ xt_lo,
    const unsigned short* __restrict__ wtt_hi, const unsigned short* __restrict__ wtt_lo,
    unsigned short* __restrict__ q_hi, unsigned short* __restrict__ q_lo,
    unsigned short* __restrict__ k_hi, unsigned short* __restrict__ k_lo,
    unsigned short* __restrict__ vtt)
{
    __shared__ __align__(16) unsigned short lds[2][12288];  // 48 KB
    int z = blockIdx.y;
    int mt = blockIdx.x;                       // 0..255
    int tid = threadIdx.x;
    int wave = tid >> 6, lane = tid & 63;
    int c15 = lane & 15, kg = lane >> 4;
    int mrow = wave >> 1, ncol = wave & 1;     // 2x2 wave grid

    const unsigned short* Ah0 = xt_hi + (size_t)mt * 32 * 2048;
    const unsigned short* Al0 = xt_lo + (size_t)mt * 32 * 2048;
    const unsigned short* Bh0 = wtt_hi + (size_t)z * 32 * 4096;
    const unsigned short* Bl0 = wtt_lo + (size_t)z * 32 * 4096;

    float4v acc[2][4];
#pragma unroll
    for (int i = 0; i < 2; i++)
#pragma unroll
        for (int j = 0; j < 4; j++) acc[i][j] = (float4v)0.0f;

    auto stage = [&](int buf, int ks) {
        unsigned short* Lb = lds[buf];
        const unsigned short* Ah = Ah0 + ks * 2048;
        const unsigned short* Al = Al0 + ks * 2048;
        const unsigned short* Bh = Bh0 + ks * 4096;
        const unsigned short* Bl = Bl0 + ks * 4096;
        int lo8 = lane * 8;
        if (z < 2) {
#pragma unroll
            for (int i = 0; i < 6; i++) {
                int ch = wave * 6 + i;
                const unsigned short* g;
                unsigned short* l;
                if (ch < 4)       { g = Ah + ch * 512;        l = Lb + ch * 512; }
                else if (ch < 8)  { g = Al + (ch - 4) * 512;  l = Lb + 2048 + (ch - 4) * 512; }
                else if (ch < 16) { g = Bh + (ch - 8) * 512;  l = Lb + 4096 + (ch - 8) * 512; }
                else              { g = Bl + (ch - 16) * 512; l = Lb + 8192 + (ch - 16) * 512; }
                gll16(g + lo8, l + lo8);
            }
        } else {
#pragma unroll
            for (int i = 0; i < 3; i++) {
                int ch = wave * 3 + i;   // 0..11
                const unsigned short* g;
                unsigned short* l;
                if (ch < 4) { g = Ah + ch * 512;       l = Lb + ch * 512; }
                else        { g = Bh + (ch - 4) * 512; l = Lb + 4096 + (ch - 4) * 512; }
                gll16(g + lo8, l + lo8);
            }
        }
    };

    stage(0, 0);

    for (int ks = 0; ks < 32; ks++) {
        __syncthreads();
        if (ks + 1 < 32) stage((ks + 1) & 1, ks + 1);
        const unsigned short* Lb = lds[ks & 1];

        short8 ah[2], al[2], bh[4], bl[4];
#pragma unroll
        for (int mi = 0; mi < 2; mi++) {
            int row = mrow * 32 + mi * 16 + c15;
            ah[mi] = *(const short8*)(Lb + row * 32 + kg * 8);
        }
#pragma unroll
        for (int ni = 0; ni < 4; ni++) {
            int row = ncol * 64 + ni * 16 + c15;
            bh[ni] = *(const short8*)(Lb + 4096 + row * 32 + kg * 8);
        }
        if (z < 2) {
#pragma unroll
            for (int mi = 0; mi < 2; mi++) {
                int row = mrow * 32 + mi * 16 + c15;
                al[mi] = *(const short8*)(Lb + 2048 + row * 32 + kg * 8);
            }
#pragma unroll
            for (int ni = 0; ni < 4; ni++) {
                int row = ncol * 64 + ni * 16 + c15;
                bl[ni] = *(const short8*)(Lb + 8192 + row * 32 + kg * 8);
            }
#pragma unroll
            for (int mi = 0; mi < 2; mi++)
#pragma unroll
                for (int ni = 0; ni < 4; ni++) {
                    acc[mi][ni] = MFMA16(ah[mi], bh[ni], acc[mi][ni]);
                    acc[mi][ni] = MFMA16(ah[mi], bl[ni], acc[mi][ni]);
                    acc[mi][ni] = MFMA16(al[mi], bh[ni], acc[mi][ni]);
                }
        } else {
#pragma unroll
            for (int mi = 0; mi < 2; mi++)
#pragma unroll
                for (int ni = 0; ni < 4; ni++)
                    acc[mi][ni] = MFMA16(ah[mi], bh[ni], acc[mi][ni]);
        }
    }

    if (z < 2) {
        unsigned short* oh = (z == 0) ? q_hi : k_hi;
        unsigned short* ol = (z == 0) ? q_lo : k_lo;
#pragma unroll
        for (int mi = 0; mi < 2; mi++) {
#pragma unroll
            for (int ni = 0; ni < 4; ni++) {
                int h = ncol * 64 + ni * 16 + c15;
#pragma unroll
                for (int r = 0; r < 4; r++) {
                    int t = mt * 64 + mrow * 32 + mi * 16 + kg * 4 + r;
                    float v = acc[mi][ni][r];
                    unsigned short hh = f2bf(v);
                    unsigned short ll = f2bf(v - bf2f(hh));
                    // swizzled: block (h>>3) of row t -> (h>>3) ^ (t&15)
                    size_t o = (size_t)t * Hn + (((h >> 3) ^ (t & 15)) << 3) + (h & 7);
                    oh[o] = hh;
                    ol[o] = ll;
                }
            }
        }
    } else {
        int b = mt >> 5;
#pragma unroll
        for (int mi = 0; mi < 2; mi++) {
            int t0 = (mt & 31) * 64 + mrow * 32 + mi * 16 + kg * 4;
            int sc = t0 >> 5, so = t0 & 31;
#pragma unroll
            for (int ni = 0; ni < 4; ni++) {
                int h = ncol * 64 + ni * 16 + c15;
                short4v pk;
#pragma unroll
                for (int r = 0; r < 4; r++) pk[r] = (short)f2bf(acc[mi][ni][r]);
                // swizzled: block (so>>3) of row h -> (so>>3) ^ ((h>>1)&3)
                int so2 = ((((so >> 3) ^ ((h >> 1) & 3))) << 3) | (so & 7);
                *(short4v*)(vtt + (((size_t)b * 64 + sc) * 128 + h) * 32 + so2) = pk;
            }
        }
    }
}

// ---------------------------------------------------------------------------
// Kernel 2: column softmax stats PARTIALS. t-loop of column tile sj split
// into nch = ((31-sj)>>3)+1 even chunks. Single-buffer staging (R11).
// grid (80, B), heavy (sj small) first.
// ---------------------------------------------------------------------------
__global__ __launch_bounds__(256) void stats_part_kernel(
    const unsigned short* __restrict__ q_hi, const unsigned short* __restrict__ q_lo,
    const unsigned short* __restrict__ k_hi, const unsigned short* __restrict__ k_lo,
    float* __restrict__ m_part, float* __restrict__ l_part)
{
    __shared__ __align__(16) unsigned short lds[8192];  // 16 KB, single buffer
    int tid = threadIdx.x;
    int wave = tid >> 6, lane = tid & 63;
    int c15 = lane & 15, kg = lane >> 4;
    int b = blockIdx.y;

    // map blockIdx.x -> (sj, ci); sj ascending = heavy first
    int rem = (int)blockIdx.x, sj, nch = 1;
    for (sj = 0; sj < 32; sj++) {
        nch = ((31 - sj) >> 3) + 1;
        if (rem < nch) break;
        rem -= nch;
    }
    int ci = rem;
    int c0 = 2 * sj;
    int len = 64 - c0;
    int cbase = len / nch, ext = len % nch;
    int cs = c0 + ci * cbase + (ci < ext ? ci : ext);
    int ce = cs + cbase + (ci < ext ? 1 : 0);

    int s_base = sj * 64 + wave * 16;

    // A fragments: wave's 16 k-rows; s&15 == c15 (s_base is x16-aligned)
    short8 a_h[4], a_l[4];
    {
        int s = s_base + c15;
        const unsigned short* kr = k_hi + ((size_t)(b * Tn + s)) * Hn;
        const unsigned short* krl = k_lo + ((size_t)(b * Tn + s)) * Hn;
#pragma unroll
        for (int st = 0; st < 4; st++) {
            int off = ((st * 4 + kg) ^ c15) * 8;
            a_h[st] = *(const short8*)(kr + off);
            a_l[st] = *(const short8*)(krl + off);
        }
    }
    float m[4], l[4];
#pragma unroll
    for (int r = 0; r < 4; r++) { m[r] = -3.0e38f; l[r] = 0.0f; }

    auto stage = [&](int c) {
        const unsigned short* Qh = q_hi + ((size_t)b * Tn + c * 32) * Hn;
        const unsigned short* Ql = q_lo + ((size_t)b * Tn + c * 32) * Hn;
        int lo8 = lane * 8;
#pragma unroll
        for (int i = 0; i < 4; i++) {
            int ch = wave * 4 + i;   // 0..15
            const unsigned short* g;
            unsigned short* ld;
            if (ch < 8) { g = Qh + ch * 512;       ld = lds + ch * 512; }
            else        { g = Ql + (ch - 8) * 512; ld = lds + 4096 + (ch - 8) * 512; }
            gll16(g + lo8, ld + lo8);
        }
    };

    for (int c = cs; c < ce; c++) {
        stage(c);
        __syncthreads();   // stage complete (vmcnt drained per-wave + join)
#pragma unroll
        for (int half = 0; half < 2; half++) {
            int t16 = c * 32 + half * 16;
            int tl = half * 16 + c15;
            float4v a1 = (float4v)0.0f, a2 = (float4v)0.0f, a3 = (float4v)0.0f;
#pragma unroll
            for (int st = 0; st < 4; st++) {
                // swizzled block ((st*4+kg) ^ (t&15)); t&15 == c15
                int off = tl * 128 + ((st * 4 + kg) ^ c15) * 8;
                short8 bh = *(const short8*)(lds + off);
                short8 bl = *(const short8*)(lds + 4096 + off);
                a1 = MFMA16(a_h[st], bh, a1);
                a2 = MFMA16(a_h[st], bl, a2);
                a3 = MFMA16(a_l[st], bh, a3);
            }
            int t = t16 + c15;
#pragma unroll
            for (int r = 0; r < 4; r++) {
                float attv = (a1[r] + a2[r] + a3[r]) * SQRTH;
                int s_row = s_base + kg * 4 + r;
                bool valid = (t >= s_row);
                float cand = valid ? attv : -3.0e38f;
                float mn = fmaxf(m[r], cand);
                l[r] = l[r] * __expf(m[r] - mn) + (valid ? __expf(attv - mn) : 0.0f);
                m[r] = mn;
            }
        }
        __syncthreads();   // all reads done before next stage overwrites
    }
    // merge t-subsets across the 16 lanes sharing kg
#pragma unroll
    for (int mask = 1; mask < 16; mask <<= 1) {
#pragma unroll
        for (int r = 0; r < 4; r++) {
            float mo = __shfl_xor(m[r], mask);
            float lo2 = __shfl_xor(l[r], mask);
            float mn = fmaxf(m[r], mo);
            l[r] = l[r] * __expf(m[r] - mn) + lo2 * __expf(mo - mn);
            m[r] = mn;
        }
    }
    if (c15 == 0) {
#pragma unroll
        for (int r = 0; r < 4; r++) {
            int sl = wave * 16 + kg * 4 + r;           // 0..63 within tile
            size_t d = ((((size_t)b * 32 + sj) * 4 + ci) * 64) + sl;
            m_part[d] = m[r];
            l_part[d] = l[r];
        }
    }
}

// ---------------------------------------------------------------------------
// Kernel 2b: merge stats partials -> (m_st, il_st). 16384 columns.
// ---------------------------------------------------------------------------
__global__ __launch_bounds__(256) void stats_combine_kernel(
    const float* __restrict__ m_part, const float* __restrict__ l_part,
    float* __restrict__ m_st, float* __restrict__ il_st)
{
    int g = blockIdx.x * 256 + threadIdx.x;   // 0..16383
    int s = g & 2047, b = g >> 11;
    int sj = s >> 6, sl = s & 63;
    int nch = ((31 - sj) >> 3) + 1;
    size_t base = (((size_t)b * 32 + sj) * 4) * 64 + sl;
    float M = m_part[base];
    float L = l_part[base];
    for (int ci = 1; ci < nch; ci++) {
        float mi = m_part[base + (size_t)ci * 64];
        float li = l_part[base + (size_t)ci * 64];
        float mn = fmaxf(M, mi);
        L = L * __expf(M - mn) + li * __expf(mi - mn);
        M = mn;
    }
    m_st[(size_t)b * Tn + s] = M;
    il_st[(size_t)b * Tn + s] = 1.0f / L;
}

// ---------------------------------------------------------------------------
// Kernel 3: output PARTIALS. s-loop of row tile tj split into nch = tj/8+1
// even chunks; fp32 partial tiles to workspace. Single-buffer staging (R11).
// grid (80, B), heavy (tj large) first.
// ---------------------------------------------------------------------------
__global__ __launch_bounds__(256) void out_part_kernel(
    const unsigned short* __restrict__ q_hi, const unsigned short* __restrict__ q_lo,
    const unsigned short* __restrict__ k_hi, const unsigned short* __restrict__ k_lo,
    const unsigned short* __restrict__ vtt,
    const float* __restrict__ m_st, const float* __restrict__ il_st,
    float* __restrict__ part_out)
{
    __shared__ __align__(16) unsigned short lds[12288];      // 24 KB, single
    __shared__ __align__(16) unsigned short pbuf[4][16][40]; // 5 KB
    int tid = threadIdx.x;
    int wave = tid >> 6, lane = tid & 63;
    int c15 = lane & 15, kg = lane >> 4;
    int b = blockIdx.y;

    // map blockIdx.x -> (tj, ci); tj descending = heavy first
    int rem = (int)blockIdx.x, tj, nch = 1;
    for (tj = 31; tj >= 0; tj--) {
        nch = (tj >> 3) + 1;
        if (rem < nch) break;
        rem -= nch;
    }
    int ci = rem;
    int len = 2 * tj + 2;
    int cbase = len / nch, ext = len % nch;
    int cs = ci * cbase + (ci < ext ? ci : ext);
    int ce = cs + cbase + (ci < ext ? 1 : 0);

    int t_base = tj * 64 + wave * 16;

    // A fragments: wave's 16 q-rows; t&15 == c15
    short8 qa_h[4], qa_l[4];
    {
        int t = t_base + c15;
        const unsigned short* qr = q_hi + ((size_t)(b * Tn + t)) * Hn;
        const unsigned short* qrl = q_lo + ((size_t)(b * Tn + t)) * Hn;
#pragma unroll
        for (int st = 0; st < 4; st++) {
            int off = ((st * 4 + kg) ^ c15) * 8;
            qa_h[st] = *(const short8*)(qr + off);
            qa_l[st] = *(const short8*)(qrl + off);
        }
    }
    float4v oacc[8];
#pragma unroll
    for (int i = 0; i < 8; i++) oacc[i] = (float4v)0.0f;

    auto stage = [&](int c) {
        const unsigned short* Kh = k_hi + ((size_t)b * Tn + c * 32) * Hn;
        const unsigned short* Kl = k_lo + ((size_t)b * Tn + c * 32) * Hn;
        const unsigned short* Vv = vtt + ((size_t)b * 64 + c) * (128 * 32);
        int lo8 = lane * 8;
#pragma unroll
        for (int i = 0; i < 6; i++) {
            int ch = wave * 6 + i;   // 0..23
            const unsigned short* g;
            unsigned short* ld;
            if (ch < 8)       { g = Kh + ch * 512;        ld = lds + ch * 512; }
            else if (ch < 16) { g = Kl + (ch - 8) * 512;  ld = lds + 4096 + (ch - 8) * 512; }
            else              { g = Vv + (ch - 16) * 512; ld = lds + 8192 + (ch - 16) * 512; }
            gll16(g + lo8, ld + lo8);
        }
    };

    for (int c = cs; c < ce; c++) {
        stage(c);
        __syncthreads();   // stage complete
#pragma unroll
        for (int half = 0; half < 2; half++) {
            int s16 = c * 32 + half * 16;
            int sl = half * 16 + c15;
            float4v a1 = (float4v)0.0f, a2 = (float4v)0.0f, a3 = (float4v)0.0f;
#pragma unroll
            for (int st = 0; st < 4; st++) {
                // swizzled block ((st*4+kg) ^ (s&15)); s&15 == c15
                int off = sl * 128 + ((st * 4 + kg) ^ c15) * 8;
                short8 bh = *(const short8*)(lds + off);
                short8 bl = *(const short8*)(lds + 4096 + off);
                a1 = MFMA16(qa_h[st], bh, a1);
                a2 = MFMA16(qa_h[st], bl, a2);
                a3 = MFMA16(qa_l[st], bh, a3);
            }
            float msv = m_st[b * Tn + s16 + c15];
            float ilv = il_st[b * Tn + s16 + c15];
#pragma unroll
            for (int r = 0; r < 4; r++) {
                int t = t_base + kg * 4 + r;
                float attv = (a1[r] + a2[r] + a3[r]) * SQRTH;
                // clamp: att <= column max for true data (ULP-exact safety)
                float earg = fminf(attv - msv, 0.0f);
                float p = (t >= s16 + c15) ? __expf(earg) * ilv : 0.0f;
                pbuf[wave][kg * 4 + r][c15 + half * 16] = f2bf(p);
            }
        }
        // C-layout -> A-layout via LDS (wave-internal, DS pipe in-order)
        short8 pa = *(const short8*)&pbuf[wave][c15][kg * 8];
#pragma unroll
        for (int nt = 0; nt < 8; nt++) {
            // vtt row h = nt*16+c15; swizzled block kg ^ ((h>>1)&3),
            // (h>>1)&3 == (c15>>1)&3 since nt*16 is a multiple of 8 in h>>1
            int voff = (nt * 16 + c15) * 32 + ((kg ^ ((c15 >> 1) & 3)) * 8);
            short8 vb = *(const short8*)(lds + 8192 + voff);
            oacc[nt] = MFMA16(pa, vb, oacc[nt]);
        }
        __syncthreads();   // all reads done before next stage overwrites
    }
    // partial tile store: part[b][tj][ci][t_local 64][h 128]
    float* po = part_out + ((((size_t)b * 32 + tj) * 4 + ci) * 64) * 128;
#pragma unroll
    for (int nt = 0; nt < 8; nt++) {
        int h = nt * 16 + c15;
#pragma unroll
        for (int r = 0; r < 4; r++) {
            int tl = wave * 16 + kg * 4 + r;
            po[(size_t)tl * 128 + h] = oacc[nt][r];
        }
    }
}

// ---------------------------------------------------------------------------
// Kernel 3b: sum output partials -> out. 2M floats, float4 loads/stores.
// ---------------------------------------------------------------------------
__global__ __launch_bounds__(256) void out_combine_kernel(
    const float* __restrict__ part_out, float* __restrict__ out)
{
    int g = blockIdx.x * 256 + threadIdx.x;   // 0..524287 (float4 units)
    int h4 = g & 31;
    int t = (g >> 5) & 2047;
    int b = g >> 16;
    int tj = t >> 6, tl = t & 63;
    int nch = (tj >> 3) + 1;
    const float4v* p = (const float4v*)(part_out
        + ((((size_t)b * 32 + tj) * 4) * 64 + tl) * 128) + h4;
    float4v acc = p[0];
    for (int ci = 1; ci < nch; ci++) acc += p[(size_t)ci * 2048];  // slot = 8192 floats
    *((float4v*)(out + ((size_t)b * Tn + t) * Hn) + h4) = acc;
}

// ---------------------------------------------------------------------------
extern "C" void kernel_launch(void* const* d_in, const int* in_sizes, int n_in,
                              void* d_out, int out_size, void* d_ws, size_t ws_size,
                              hipStream_t stream)
{
    (void)in_sizes; (void)n_in; (void)out_size; (void)ws_size;
    const float* x  = (const float*)d_in[0];
    const float* Wk = (const float*)d_in[1];
    const float* Wq = (const float*)d_in[2];
    const float* Wv = (const float*)d_in[3];
    float* out = (float*)d_out;

    const size_t NQ = (size_t)Bn * Tn * Hn;        // 2,097,152
    const size_t NX = (size_t)Bn * Tn * En;        // 16,777,216
    unsigned short* q_hi = (unsigned short*)d_ws;
    unsigned short* q_lo = q_hi + NQ;
    unsigned short* k_hi = q_lo + NQ;
    unsigned short* k_lo = k_hi + NQ;
    unsigned short* vtt  = k_lo + NQ;
    unsigned short* xt_hi = vtt + NQ;
    unsigned short* xt_lo = xt_hi + NX;
    unsigned short* wtt_hi = xt_lo + NX;
    unsigned short* wtt_lo = wtt_hi + (size_t)3 * Hn * En;
    float* m_st  = (float*)(wtt_lo + (size_t)3 * Hn * En);
    float* il_st = m_st + (size_t)Bn * Tn;
    // total ws use: ~89.4 MB — identical extent to the validated R7 layout

    // xt_* is dead after proj_kernel: alias the attention partial buffers
    // onto it. part_out = 8*32*4*64*128 floats = 33.5 MB (== sizeof xt_hi).
    float* part_out = (float*)xt_hi;
    float* m_part   = (float*)xt_lo;               // 8*32*4*64 = 64K floats
    float* l_part   = m_part + (size_t)Bn * 32 * 4 * 64;

    wtrans_kernel<<<dim3(192), 256, 0, stream>>>(Wq, Wk, Wv, wtt_hi, wtt_lo);
    xconv_kernel<<<dim3(8192), 256, 0, stream>>>(x, xt_hi, xt_lo);
    proj_kernel<<<dim3(256, 3), 256, 0, stream>>>(xt_hi, xt_lo, wtt_hi, wtt_lo,
                                                  q_hi, q_lo, k_hi, k_lo, vtt);
    stats_part_kernel<<<dim3(80, Bn), 256, 0, stream>>>(q_hi, q_lo, k_hi, k_lo,
                                                        m_part, l_part);
    stats_combine_kernel<<<dim3(64), 256, 0, stream>>>(m_part, l_part, m_st, il_st);
    out_part_kernel<<<dim3(80, Bn), 256, 0, stream>>>(q_hi, q_lo, k_hi, k_lo, vtt,
                                                      m_st, il_st, part_out);
    out_combine_kernel<<<dim3(2048), 256, 0, stream>>>(part_out, out);
}

// Round 4
// 218.919 us; speedup vs baseline: 1.4372x; 1.0538x over previous
//
#include <hip/hip_runtime.h>
#include <math.h>

#define Bn 8
#define Tn 2048
#define En 1024
#define Hn 128
#define SQRTH 11.313708498984761f

typedef __attribute__((ext_vector_type(8))) short short8;
typedef __attribute__((ext_vector_type(4))) short short4v;
typedef __attribute__((ext_vector_type(4))) float float4v;

#define MFMA16(a, b, c) __builtin_amdgcn_mfma_f32_16x16x32_bf16((a), (b), (c), 0, 0, 0)

static __device__ __forceinline__ unsigned short f2bf(float f) {
    unsigned u = __float_as_uint(f);
    u += 0x7FFFu + ((u >> 16) & 1u);   // RNE
    return (unsigned short)(u >> 16);
}
static __device__ __forceinline__ float bf2f(unsigned short h) {
    return __uint_as_float(((unsigned)h) << 16);
}

// async global->LDS, 16 B per lane. LDS dest is wave-uniform base + lane*16.
static __device__ __forceinline__ void gll16(const unsigned short* g, unsigned short* l) {
    __builtin_amdgcn_global_load_lds(
        (const __attribute__((address_space(1))) unsigned int*)g,
        (__attribute__((address_space(3))) unsigned int*)l, 16, 0, 0);
}

// ---------------------------------------------------------------------------
// SWIZZLES (baked into GLOBAL layouts; global_load_lds forces LDS == global
// order, so all readers adjust):
//  - q/k rows (128 shorts = 16 x 16B blocks): block j of row t at j^(t&15).
//  - vtt rows (32 shorts = 4 blocks): block j of row h at j^((h>>1)&3).
//  - R12: xt/wtt rows (32 shorts = 4 blocks): block j of row r at j^(r&3).
//    proj's fragment reads (row==c15 per lane) previously hit only bank
//    groups {0,1,4,5} mod 8 -> 2-way conflict (3.9M cycles); with the
//    swizzle each 32-lane phase covers all 8 groups x4 -> conflict-free.
//
// R9:  chunked stats/out partials + combines. R10: failed. R11: single-
// buffer staging in chunked kernels (delete dbuf bug class); passed 230.7.
// R12: proj bank-conflict swizzle + hoisted staging addresses; chunk
// divisor 8->4 (max 8 chunks, <=8 iters, 144 blocks/batch = 4.5/CU).
// ---------------------------------------------------------------------------

// ---------------------------------------------------------------------------
// Kernel 0: W (E,H) fp32 -> K-tiled split bf16 wtt[z][ks][128 h][32 k],
// 16B blocks swizzled j^(h&3).
// ---------------------------------------------------------------------------
__global__ __launch_bounds__(256) void wtrans_kernel(
    const float* __restrict__ Wq, const float* __restrict__ Wk, const float* __restrict__ Wv,
    unsigned short* __restrict__ wtt_hi, unsigned short* __restrict__ wtt_lo)
{
    int t = blockIdx.x * 256 + threadIdx.x;   // 0..49151
    int kc8 = t & 3;
    int hh = (t >> 2) & 127;
    int ks = (t >> 9) & 31;
    int z = t >> 14;
    const float* W = (z == 0) ? Wq : ((z == 1) ? Wk : Wv);
    short8 h8, l8;
#pragma unroll
    for (int j = 0; j < 8; j++) {
        int e = ks * 32 + kc8 * 8 + j;
        float v = W[(size_t)e * Hn + hh];
        unsigned short hi = f2bf(v);
        h8[j] = (short)hi;
        l8[j] = (short)f2bf(v - bf2f(hi));
    }
    size_t d = (((size_t)z * 32 + ks) * 4096) + (size_t)hh * 32
             + (size_t)(kc8 ^ (hh & 3)) * 8;            // R12 swizzle
    *(short8*)(wtt_hi + d) = h8;
    *(short8*)(wtt_lo + d) = l8;
}

// ---------------------------------------------------------------------------
// Kernel 0b: x fp32 -> K-tiled split bf16 xt[mt][ks][64 r][32 k],
// 16B blocks swizzled j^(r&3).
// ---------------------------------------------------------------------------
__global__ __launch_bounds__(256) void xconv_kernel(
    const float* __restrict__ x,
    unsigned short* __restrict__ xt_hi, unsigned short* __restrict__ xt_lo)
{
    int g = blockIdx.x * 256 + threadIdx.x;   // 0..2097151
    int kc8 = g & 3;
    int rr = (g >> 2) & 63;
    int ks = (g >> 8) & 31;
    int mt = g >> 13;
    size_t src = ((size_t)mt * 64 + rr) * En + ks * 32 + kc8 * 8;
    float4v f0 = *(const float4v*)(x + src);
    float4v f1 = *(const float4v*)(x + src + 4);
    short8 h, l;
#pragma unroll
    for (int j = 0; j < 4; j++) {
        unsigned short h0 = f2bf(f0[j]);
        h[j] = (short)h0; l[j] = (short)f2bf(f0[j] - bf2f(h0));
        unsigned short h1 = f2bf(f1[j]);
        h[j + 4] = (short)h1; l[j + 4] = (short)f2bf(f1[j] - bf2f(h1));
    }
    size_t d = (size_t)(g >> 2) * 32 + (size_t)(kc8 ^ (rr & 3)) * 8;  // R12
    *(short8*)(xt_hi + d) = h;
    *(short8*)(xt_lo + d) = l;
}

// ---------------------------------------------------------------------------
// Kernel 1: projections, LDS double-buffered GEMM. R12: swizzle-aware
// fragment reads (kg ^ (c15&3)); staging chunk addresses hoisted out of
// the ks loop into register pointer/stride arrays.
// ---------------------------------------------------------------------------
__global__ __launch_bounds__(256) void proj_kernel(
    const unsigned short* __restrict__ xt_hi, const unsigned short* __restrict__ xt_lo,
    const unsigned short* __restrict__ wtt_hi, const unsigned short* __restrict__ wtt_lo,
    unsigned short* __restrict__ q_hi, unsigned short* __restrict__ q_lo,
    unsigned short* __restrict__ k_hi, unsigned short* __restrict__ k_lo,
    unsigned short* __restrict__ vtt)
{
    __shared__ __align__(16) unsigned short lds[2][12288];  // 48 KB
    int z = blockIdx.y;
    int mt = blockIdx.x;                       // 0..255
    int tid = threadIdx.x;
    int wave = tid >> 6, lane = tid & 63;
    int c15 = lane & 15, kg = lane >> 4;
    int sb = c15 & 3;                          // R12 read-swizzle selector
    int mrow = wave >> 1, ncol = wave & 1;     // 2x2 wave grid

    const unsigned short* Ah0 = xt_hi + (size_t)mt * 32 * 2048;
    const unsigned short* Al0 = xt_lo + (size_t)mt * 32 * 2048;
    const unsigned short* Bh0 = wtt_hi + (size_t)z * 32 * 4096;
    const unsigned short* Bl0 = wtt_lo + (size_t)z * 32 * 4096;

    float4v acc[2][4];
#pragma unroll
    for (int i = 0; i < 2; i++)
#pragma unroll
        for (int j = 0; j < 4; j++) acc[i][j] = (float4v)0.0f;

    // hoisted staging descriptors (R12): per-chunk global cursor, LDS
    // offset (buffer 0), and per-ks stride. Computed once.
    const unsigned short* gcur[6];
    int lbo[6];
    int gstep[6];
    if (z < 2) {
#pragma unroll
        for (int i = 0; i < 6; i++) {
            int ch = wave * 6 + i;
            if (ch < 4)       { gcur[i] = Ah0 + ch * 512;        lbo[i] = ch * 512;               gstep[i] = 2048; }
            else if (ch < 8)  { gcur[i] = Al0 + (ch - 4) * 512;  lbo[i] = 2048 + (ch - 4) * 512;  gstep[i] = 2048; }
            else if (ch < 16) { gcur[i] = Bh0 + (ch - 8) * 512;  lbo[i] = 4096 + (ch - 8) * 512;  gstep[i] = 4096; }
            else              { gcur[i] = Bl0 + (ch - 16) * 512; lbo[i] = 8192 + (ch - 16) * 512; gstep[i] = 4096; }
        }
    } else {
#pragma unroll
        for (int i = 0; i < 3; i++) {
            int ch = wave * 3 + i;   // 0..11
            if (ch < 4) { gcur[i] = Ah0 + ch * 512;       lbo[i] = ch * 512;              gstep[i] = 2048; }
            else        { gcur[i] = Bh0 + (ch - 4) * 512; lbo[i] = 4096 + (ch - 4) * 512; gstep[i] = 4096; }
        }
    }
    int lo8 = lane * 8;

    auto stage = [&](int buf) {
        unsigned short* Lb = lds[0] + buf * 12288;
        if (z < 2) {
#pragma unroll
            for (int i = 0; i < 6; i++) {
                gll16(gcur[i] + lo8, Lb + lbo[i] + lo8);
                gcur[i] += gstep[i];
            }
        } else {
#pragma unroll
            for (int i = 0; i < 3; i++) {
                gll16(gcur[i] + lo8, Lb + lbo[i] + lo8);
                gcur[i] += gstep[i];
            }
        }
    };

    stage(0);

    for (int ks = 0; ks < 32; ks++) {
        __syncthreads();
        if (ks + 1 < 32) stage((ks + 1) & 1);
        const unsigned short* Lb = lds[ks & 1];

        short8 ah[2], al[2], bh[4], bl[4];
#pragma unroll
        for (int mi = 0; mi < 2; mi++) {
            int row = mrow * 32 + mi * 16 + c15;
            ah[mi] = *(const short8*)(Lb + row * 32 + (kg ^ sb) * 8);
        }
#pragma unroll
        for (int ni = 0; ni < 4; ni++) {
            int row = ncol * 64 + ni * 16 + c15;
            bh[ni] = *(const short8*)(Lb + 4096 + row * 32 + (kg ^ sb) * 8);
        }
        if (z < 2) {
#pragma unroll
            for (int mi = 0; mi < 2; mi++) {
                int row = mrow * 32 + mi * 16 + c15;
                al[mi] = *(const short8*)(Lb + 2048 + row * 32 + (kg ^ sb) * 8);
            }
#pragma unroll
            for (int ni = 0; ni < 4; ni++) {
                int row = ncol * 64 + ni * 16 + c15;
                bl[ni] = *(const short8*)(Lb + 8192 + row * 32 + (kg ^ sb) * 8);
            }
#pragma unroll
            for (int mi = 0; mi < 2; mi++)
#pragma unroll
                for (int ni = 0; ni < 4; ni++) {
                    acc[mi][ni] = MFMA16(ah[mi], bh[ni], acc[mi][ni]);
                    acc[mi][ni] = MFMA16(ah[mi], bl[ni], acc[mi][ni]);
                    acc[mi][ni] = MFMA16(al[mi], bh[ni], acc[mi][ni]);
                }
        } else {
#pragma unroll
            for (int mi = 0; mi < 2; mi++)
#pragma unroll
                for (int ni = 0; ni < 4; ni++)
                    acc[mi][ni] = MFMA16(ah[mi], bh[ni], acc[mi][ni]);
        }
    }

    if (z < 2) {
        unsigned short* oh = (z == 0) ? q_hi : k_hi;
        unsigned short* ol = (z == 0) ? q_lo : k_lo;
#pragma unroll
        for (int mi = 0; mi < 2; mi++) {
#pragma unroll
            for (int ni = 0; ni < 4; ni++) {
                int h = ncol * 64 + ni * 16 + c15;
#pragma unroll
                for (int r = 0; r < 4; r++) {
                    int t = mt * 64 + mrow * 32 + mi * 16 + kg * 4 + r;
                    float v = acc[mi][ni][r];
                    unsigned short hh = f2bf(v);
                    unsigned short ll = f2bf(v - bf2f(hh));
                    // swizzled: block (h>>3) of row t -> (h>>3) ^ (t&15)
                    size_t o = (size_t)t * Hn + (((h >> 3) ^ (t & 15)) << 3) + (h & 7);
                    oh[o] = hh;
                    ol[o] = ll;
                }
            }
        }
    } else {
        int b = mt >> 5;
#pragma unroll
        for (int mi = 0; mi < 2; mi++) {
            int t0 = (mt & 31) * 64 + mrow * 32 + mi * 16 + kg * 4;
            int sc = t0 >> 5, so = t0 & 31;
#pragma unroll
            for (int ni = 0; ni < 4; ni++) {
                int h = ncol * 64 + ni * 16 + c15;
                short4v pk;
#pragma unroll
                for (int r = 0; r < 4; r++) pk[r] = (short)f2bf(acc[mi][ni][r]);
                // swizzled: block (so>>3) of row h -> (so>>3) ^ ((h>>1)&3)
                int so2 = ((((so >> 3) ^ ((h >> 1) & 3))) << 3) | (so & 7);
                *(short4v*)(vtt + (((size_t)b * 64 + sc) * 128 + h) * 32 + so2) = pk;
            }
        }
    }
}

// ---------------------------------------------------------------------------
// Kernel 2: column softmax stats PARTIALS. t-loop of column tile sj split
// into nch = ((31-sj)>>2)+1 even chunks (<=8 iters). Single-buffer staging.
// grid (144, B), heavy (sj small) first.
// ---------------------------------------------------------------------------
__global__ __launch_bounds__(256) void stats_part_kernel(
    const unsigned short* __restrict__ q_hi, const unsigned short* __restrict__ q_lo,
    const unsigned short* __restrict__ k_hi, const unsigned short* __restrict__ k_lo,
    float* __restrict__ m_part, float* __restrict__ l_part)
{
    __shared__ __align__(16) unsigned short lds[8192];  // 16 KB, single buffer
    int tid = threadIdx.x;
    int wave = tid >> 6, lane = tid & 63;
    int c15 = lane & 15, kg = lane >> 4;
    int b = blockIdx.y;

    // map blockIdx.x -> (sj, ci); sj ascending = heavy first
    int rem = (int)blockIdx.x, sj, nch = 1;
    for (sj = 0; sj < 32; sj++) {
        nch = ((31 - sj) >> 2) + 1;
        if (rem < nch) break;
        rem -= nch;
    }
    int ci = rem;
    int c0 = 2 * sj;
    int len = 64 - c0;
    int cbase = len / nch, ext = len % nch;
    int cs = c0 + ci * cbase + (ci < ext ? ci : ext);
    int ce = cs + cbase + (ci < ext ? 1 : 0);

    int s_base = sj * 64 + wave * 16;

    // A fragments: wave's 16 k-rows; s&15 == c15 (s_base is x16-aligned)
    short8 a_h[4], a_l[4];
    {
        int s = s_base + c15;
        const unsigned short* kr = k_hi + ((size_t)(b * Tn + s)) * Hn;
        const unsigned short* krl = k_lo + ((size_t)(b * Tn + s)) * Hn;
#pragma unroll
        for (int st = 0; st < 4; st++) {
            int off = ((st * 4 + kg) ^ c15) * 8;
            a_h[st] = *(const short8*)(kr + off);
            a_l[st] = *(const short8*)(krl + off);
        }
    }
    float m[4], l[4];
#pragma unroll
    for (int r = 0; r < 4; r++) { m[r] = -3.0e38f; l[r] = 0.0f; }

    auto stage = [&](int c) {
        const unsigned short* Qh = q_hi + ((size_t)b * Tn + c * 32) * Hn;
        const unsigned short* Ql = q_lo + ((size_t)b * Tn + c * 32) * Hn;
        int lo8 = lane * 8;
#pragma unroll
        for (int i = 0; i < 4; i++) {
            int ch = wave * 4 + i;   // 0..15
            const unsigned short* g;
            unsigned short* ld;
            if (ch < 8) { g = Qh + ch * 512;       ld = lds + ch * 512; }
            else        { g = Ql + (ch - 8) * 512; ld = lds + 4096 + (ch - 8) * 512; }
            gll16(g + lo8, ld + lo8);
        }
    };

    for (int c = cs; c < ce; c++) {
        stage(c);
        __syncthreads();   // stage complete
#pragma unroll
        for (int half = 0; half < 2; half++) {
            int t16 = c * 32 + half * 16;
            int tl = half * 16 + c15;
            float4v a1 = (float4v)0.0f, a2 = (float4v)0.0f, a3 = (float4v)0.0f;
#pragma unroll
            for (int st = 0; st < 4; st++) {
                // swizzled block ((st*4+kg) ^ (t&15)); t&15 == c15
                int off = tl * 128 + ((st * 4 + kg) ^ c15) * 8;
                short8 bh = *(const short8*)(lds + off);
                short8 bl = *(const short8*)(lds + 4096 + off);
                a1 = MFMA16(a_h[st], bh, a1);
                a2 = MFMA16(a_h[st], bl, a2);
                a3 = MFMA16(a_l[st], bh, a3);
            }
            int t = t16 + c15;
#pragma unroll
            for (int r = 0; r < 4; r++) {
                float attv = (a1[r] + a2[r] + a3[r]) * SQRTH;
                int s_row = s_base + kg * 4 + r;
                bool valid = (t >= s_row);
                float cand = valid ? attv : -3.0e38f;
                float mn = fmaxf(m[r], cand);
                l[r] = l[r] * __expf(m[r] - mn) + (valid ? __expf(attv - mn) : 0.0f);
                m[r] = mn;
            }
        }
        __syncthreads();   // all reads done before next stage overwrites
    }
    // merge t-subsets across the 16 lanes sharing kg
#pragma unroll
    for (int mask = 1; mask < 16; mask <<= 1) {
#pragma unroll
        for (int r = 0; r < 4; r++) {
            float mo = __shfl_xor(m[r], mask);
            float lo2 = __shfl_xor(l[r], mask);
            float mn = fmaxf(m[r], mo);
            l[r] = l[r] * __expf(m[r] - mn) + lo2 * __expf(mo - mn);
            m[r] = mn;
        }
    }
    if (c15 == 0) {
#pragma unroll
        for (int r = 0; r < 4; r++) {
            int sl = wave * 16 + kg * 4 + r;           // 0..63 within tile
            size_t d = ((((size_t)b * 32 + sj) * 8 + ci) * 64) + sl;
            m_part[d] = m[r];
            l_part[d] = l[r];
        }
    }
}

// ---------------------------------------------------------------------------
// Kernel 2b: merge stats partials -> (m_st, il_st). 16384 columns.
// ---------------------------------------------------------------------------
__global__ __launch_bounds__(256) void stats_combine_kernel(
    const float* __restrict__ m_part, const float* __restrict__ l_part,
    float* __restrict__ m_st, float* __restrict__ il_st)
{
    int g = blockIdx.x * 256 + threadIdx.x;   // 0..16383
    int s = g & 2047, b = g >> 11;
    int sj = s >> 6, sl = s & 63;
    int nch = ((31 - sj) >> 2) + 1;
    size_t base = (((size_t)b * 32 + sj) * 8) * 64 + sl;
    float M = m_part[base];
    float L = l_part[base];
    for (int ci = 1; ci < nch; ci++) {
        float mi = m_part[base + (size_t)ci * 64];
        float li = l_part[base + (size_t)ci * 64];
        float mn = fmaxf(M, mi);
        L = L * __expf(M - mn) + li * __expf(mi - mn);
        M = mn;
    }
    m_st[(size_t)b * Tn + s] = M;
    il_st[(size_t)b * Tn + s] = 1.0f / L;
}

// ---------------------------------------------------------------------------
// Kernel 3: output PARTIALS. s-loop of row tile tj split into nch =
// (tj>>2)+1 even chunks (<=8 iters); fp32 partial tiles to workspace.
// Single-buffer staging. grid (144, B), heavy (tj large) first.
// ---------------------------------------------------------------------------
__global__ __launch_bounds__(256) void out_part_kernel(
    const unsigned short* __restrict__ q_hi, const unsigned short* __restrict__ q_lo,
    const unsigned short* __restrict__ k_hi, const unsigned short* __restrict__ k_lo,
    const unsigned short* __restrict__ vtt,
    const float* __restrict__ m_st, const float* __restrict__ il_st,
    float* __restrict__ part_out)
{
    __shared__ __align__(16) unsigned short lds[12288];      // 24 KB, single
    __shared__ __align__(16) unsigned short pbuf[4][16][40]; // 5 KB
    int tid = threadIdx.x;
    int wave = tid >> 6, lane = tid & 63;
    int c15 = lane & 15, kg = lane >> 4;
    int b = blockIdx.y;

    // map blockIdx.x -> (tj, ci); tj descending = heavy first
    int rem = (int)blockIdx.x, tj, nch = 1;
    for (tj = 31; tj >= 0; tj--) {
        nch = (tj >> 2) + 1;
        if (rem < nch) break;
        rem -= nch;
    }
    int ci = rem;
    int len = 2 * tj + 2;
    int cbase = len / nch, ext = len % nch;
    int cs = ci * cbase + (ci < ext ? ci : ext);
    int ce = cs + cbase + (ci < ext ? 1 : 0);

    int t_base = tj * 64 + wave * 16;

    // A fragments: wave's 16 q-rows; t&15 == c15
    short8 qa_h[4], qa_l[4];
    {
        int t = t_base + c15;
        const unsigned short* qr = q_hi + ((size_t)(b * Tn + t)) * Hn;
        const unsigned short* qrl = q_lo + ((size_t)(b * Tn + t)) * Hn;
#pragma unroll
        for (int st = 0; st < 4; st++) {
            int off = ((st * 4 + kg) ^ c15) * 8;
            qa_h[st] = *(const short8*)(qr + off);
            qa_l[st] = *(const short8*)(qrl + off);
        }
    }
    float4v oacc[8];
#pragma unroll
    for (int i = 0; i < 8; i++) oacc[i] = (float4v)0.0f;

    auto stage = [&](int c) {
        const unsigned short* Kh = k_hi + ((size_t)b * Tn + c * 32) * Hn;
        const unsigned short* Kl = k_lo + ((size_t)b * Tn + c * 32) * Hn;
        const unsigned short* Vv = vtt + ((size_t)b * 64 + c) * (128 * 32);
        int lo8 = lane * 8;
#pragma unroll
        for (int i = 0; i < 6; i++) {
            int ch = wave * 6 + i;   // 0..23
            const unsigned short* g;
            unsigned short* ld;
            if (ch < 8)       { g = Kh + ch * 512;        ld = lds + ch * 512; }
            else if (ch < 16) { g = Kl + (ch - 8) * 512;  ld = lds + 4096 + (ch - 8) * 512; }
            else              { g = Vv + (ch - 16) * 512; ld = lds + 8192 + (ch - 16) * 512; }
            gll16(g + lo8, ld + lo8);
        }
    };

    for (int c = cs; c < ce; c++) {
        stage(c);
        __syncthreads();   // stage complete
#pragma unroll
        for (int half = 0; half < 2; half++) {
            int s16 = c * 32 + half * 16;
            int sl = half * 16 + c15;
            float4v a1 = (float4v)0.0f, a2 = (float4v)0.0f, a3 = (float4v)0.0f;
#pragma unroll
            for (int st = 0; st < 4; st++) {
                // swizzled block ((st*4+kg) ^ (s&15)); s&15 == c15
                int off = sl * 128 + ((st * 4 + kg) ^ c15) * 8;
                short8 bh = *(const short8*)(lds + off);
                short8 bl = *(const short8*)(lds + 4096 + off);
                a1 = MFMA16(qa_h[st], bh, a1);
                a2 = MFMA16(qa_h[st], bl, a2);
                a3 = MFMA16(qa_l[st], bh, a3);
            }
            float msv = m_st[b * Tn + s16 + c15];
            float ilv = il_st[b * Tn + s16 + c15];
#pragma unroll
            for (int r = 0; r < 4; r++) {
                int t = t_base + kg * 4 + r;
                float attv = (a1[r] + a2[r] + a3[r]) * SQRTH;
                // clamp: att <= column max for true data (ULP-exact safety)
                float earg = fminf(attv - msv, 0.0f);
                float p = (t >= s16 + c15) ? __expf(earg) * ilv : 0.0f;
                pbuf[wave][kg * 4 + r][c15 + half * 16] = f2bf(p);
            }
        }
        // C-layout -> A-layout via LDS (wave-internal, DS pipe in-order)
        short8 pa = *(const short8*)&pbuf[wave][c15][kg * 8];
#pragma unroll
        for (int nt = 0; nt < 8; nt++) {
            // vtt row h = nt*16+c15; swizzled block kg ^ ((h>>1)&3),
            // (h>>1)&3 == (c15>>1)&3 since nt*16 is a multiple of 8 in h>>1
            int voff = (nt * 16 + c15) * 32 + ((kg ^ ((c15 >> 1) & 3)) * 8);
            short8 vb = *(const short8*)(lds + 8192 + voff);
            oacc[nt] = MFMA16(pa, vb, oacc[nt]);
        }
        __syncthreads();   // all reads done before next stage overwrites
    }
    // partial tile store: part[b][tj][ci][t_local 64][h 128]
    float* po = part_out + ((((size_t)b * 32 + tj) * 8 + ci) * 64) * 128;
#pragma unroll
    for (int nt = 0; nt < 8; nt++) {
        int h = nt * 16 + c15;
#pragma unroll
        for (int r = 0; r < 4; r++) {
            int tl = wave * 16 + kg * 4 + r;
            po[(size_t)tl * 128 + h] = oacc[nt][r];
        }
    }
}

// ---------------------------------------------------------------------------
// Kernel 3b: sum output partials -> out. 2M floats, float4 loads/stores.
// ---------------------------------------------------------------------------
__global__ __launch_bounds__(256) void out_combine_kernel(
    const float* __restrict__ part_out, float* __restrict__ out)
{
    int g = blockIdx.x * 256 + threadIdx.x;   // 0..524287 (float4 units)
    int h4 = g & 31;
    int t = (g >> 5) & 2047;
    int b = g >> 16;
    int tj = t >> 6, tl = t & 63;
    int nch = (tj >> 2) + 1;
    const float4v* p = (const float4v*)(part_out
        + ((((size_t)b * 32 + tj) * 8) * 64 + tl) * 128) + h4;
    float4v acc = p[0];
    for (int ci = 1; ci < nch; ci++) acc += p[(size_t)ci * 2048];  // slot = 8192 floats
    *((float4v*)(out + ((size_t)b * Tn + t) * Hn) + h4) = acc;
}

// ---------------------------------------------------------------------------
extern "C" void kernel_launch(void* const* d_in, const int* in_sizes, int n_in,
                              void* d_out, int out_size, void* d_ws, size_t ws_size,
                              hipStream_t stream)
{
    (void)in_sizes; (void)n_in; (void)out_size; (void)ws_size;
    const float* x  = (const float*)d_in[0];
    const float* Wk = (const float*)d_in[1];
    const float* Wq = (const float*)d_in[2];
    const float* Wv = (const float*)d_in[3];
    float* out = (float*)d_out;

    const size_t NQ = (size_t)Bn * Tn * Hn;        // 2,097,152
    const size_t NX = (size_t)Bn * Tn * En;        // 16,777,216
    unsigned short* q_hi = (unsigned short*)d_ws;
    unsigned short* q_lo = q_hi + NQ;
    unsigned short* k_hi = q_lo + NQ;
    unsigned short* k_lo = k_hi + NQ;
    unsigned short* vtt  = k_lo + NQ;
    unsigned short* xt_hi = vtt + NQ;
    unsigned short* xt_lo = xt_hi + NX;
    unsigned short* wtt_hi = xt_lo + NX;
    unsigned short* wtt_lo = wtt_hi + (size_t)3 * Hn * En;
    float* m_st  = (float*)(wtt_lo + (size_t)3 * Hn * En);
    float* il_st = m_st + (size_t)Bn * Tn;
    // total ws use: ~89.4 MB — identical extent to the validated R7 layout

    // Dead-after-proj aliases:
    //  part_out = xt region: 8*32*8*64*128 fp32 = 67.1 MB == sizeof(xt_hi+xt_lo)
    //  m_part/l_part = wtt region: 8*32*8*64 fp32 = 512 KB each (<= 768 KB)
    float* part_out = (float*)xt_hi;
    float* m_part   = (float*)wtt_hi;
    float* l_part   = (float*)wtt_lo;

    wtrans_kernel<<<dim3(192), 256, 0, stream>>>(Wq, Wk, Wv, wtt_hi, wtt_lo);
    xconv_kernel<<<dim3(8192), 256, 0, stream>>>(x, xt_hi, xt_lo);
    proj_kernel<<<dim3(256, 3), 256, 0, stream>>>(xt_hi, xt_lo, wtt_hi, wtt_lo,
                                                  q_hi, q_lo, k_hi, k_lo, vtt);
    stats_part_kernel<<<dim3(144, Bn), 256, 0, stream>>>(q_hi, q_lo, k_hi, k_lo,
                                                         m_part, l_part);
    stats_combine_kernel<<<dim3(64), 256, 0, stream>>>(m_part, l_part, m_st, il_st);
    out_part_kernel<<<dim3(144, Bn), 256, 0, stream>>>(q_hi, q_lo, k_hi, k_lo, vtt,
                                                       m_st, il_st, part_out);
    out_combine_kernel<<<dim3(2048), 256, 0, stream>>>(part_out, out);
}

// Round 5
// 208.737 us; speedup vs baseline: 1.5073x; 1.0488x over previous
//
#include <hip/hip_runtime.h>
#include <math.h>

#define Bn 8
#define Tn 2048
#define En 1024
#define Hn 128
#define SQRTH 11.313708498984761f

typedef __attribute__((ext_vector_type(8))) short short8;
typedef __attribute__((ext_vector_type(4))) short short4v;
typedef __attribute__((ext_vector_type(4))) float float4v;

#define MFMA16(a, b, c) __builtin_amdgcn_mfma_f32_16x16x32_bf16((a), (b), (c), 0, 0, 0)

static __device__ __forceinline__ unsigned short f2bf(float f) {
    unsigned u = __float_as_uint(f);
    u += 0x7FFFu + ((u >> 16) & 1u);   // RNE
    return (unsigned short)(u >> 16);
}
static __device__ __forceinline__ float bf2f(unsigned short h) {
    return __uint_as_float(((unsigned)h) << 16);
}

// async global->LDS, 16 B per lane. LDS dest is wave-uniform base + lane*16.
static __device__ __forceinline__ void gll16(const unsigned short* g, unsigned short* l) {
    __builtin_amdgcn_global_load_lds(
        (const __attribute__((address_space(1))) unsigned int*)g,
        (__attribute__((address_space(3))) unsigned int*)l, 16, 0, 0);
}

// ---------------------------------------------------------------------------
// SWIZZLES (baked into GLOBAL layouts; global_load_lds forces LDS == global
// order, so all readers adjust):
//  - q/k rows (128 shorts = 16 x 16B blocks): block j of row t at j^(t&15).
//  - vtt rows (32 shorts = 4 blocks): block j of row h at j^((h>>1)&3).
//  - xt/wtt rows (32 shorts = 4 blocks): block j of row r at j^(r&3).
//
// R9:  chunked stats/out partials + combines. R11: single-buffer staging in
// chunked kernels (delete dbuf bug class); 230.7. R12: proj bank-conflict
// swizzle + hoisted staging; chunk divisor 4 (144 blocks/batch); 218.9.
// R13: XCD batch affinity. out_part showed FETCH 60.6 MB vs ~20 MB ideal:
// grid (chunks, B) round-robins consecutive chunks of one batch across
// XCDs, so every XCD touches all 8 batches (20 MB >> 4 MB L2). Transpose
// grid to (B, chunks): linear wg id = b + 8*chunk -> XCD = b; each XCD's
// working set = one batch (~2.5 MB) -> L2-resident staging.
// ---------------------------------------------------------------------------

// ---------------------------------------------------------------------------
// Kernel 0: W (E,H) fp32 -> K-tiled split bf16 wtt[z][ks][128 h][32 k],
// 16B blocks swizzled j^(h&3).
// ---------------------------------------------------------------------------
__global__ __launch_bounds__(256) void wtrans_kernel(
    const float* __restrict__ Wq, const float* __restrict__ Wk, const float* __restrict__ Wv,
    unsigned short* __restrict__ wtt_hi, unsigned short* __restrict__ wtt_lo)
{
    int t = blockIdx.x * 256 + threadIdx.x;   // 0..49151
    int kc8 = t & 3;
    int hh = (t >> 2) & 127;
    int ks = (t >> 9) & 31;
    int z = t >> 14;
    const float* W = (z == 0) ? Wq : ((z == 1) ? Wk : Wv);
    short8 h8, l8;
#pragma unroll
    for (int j = 0; j < 8; j++) {
        int e = ks * 32 + kc8 * 8 + j;
        float v = W[(size_t)e * Hn + hh];
        unsigned short hi = f2bf(v);
        h8[j] = (short)hi;
        l8[j] = (short)f2bf(v - bf2f(hi));
    }
    size_t d = (((size_t)z * 32 + ks) * 4096) + (size_t)hh * 32
             + (size_t)(kc8 ^ (hh & 3)) * 8;            // R12 swizzle
    *(short8*)(wtt_hi + d) = h8;
    *(short8*)(wtt_lo + d) = l8;
}

// ---------------------------------------------------------------------------
// Kernel 0b: x fp32 -> K-tiled split bf16 xt[mt][ks][64 r][32 k],
// 16B blocks swizzled j^(r&3).
// ---------------------------------------------------------------------------
__global__ __launch_bounds__(256) void xconv_kernel(
    const float* __restrict__ x,
    unsigned short* __restrict__ xt_hi, unsigned short* __restrict__ xt_lo)
{
    int g = blockIdx.x * 256 + threadIdx.x;   // 0..2097151
    int kc8 = g & 3;
    int rr = (g >> 2) & 63;
    int ks = (g >> 8) & 31;
    int mt = g >> 13;
    size_t src = ((size_t)mt * 64 + rr) * En + ks * 32 + kc8 * 8;
    float4v f0 = *(const float4v*)(x + src);
    float4v f1 = *(const float4v*)(x + src + 4);
    short8 h, l;
#pragma unroll
    for (int j = 0; j < 4; j++) {
        unsigned short h0 = f2bf(f0[j]);
        h[j] = (short)h0; l[j] = (short)f2bf(f0[j] - bf2f(h0));
        unsigned short h1 = f2bf(f1[j]);
        h[j + 4] = (short)h1; l[j + 4] = (short)f2bf(f1[j] - bf2f(h1));
    }
    size_t d = (size_t)(g >> 2) * 32 + (size_t)(kc8 ^ (rr & 3)) * 8;  // R12
    *(short8*)(xt_hi + d) = h;
    *(short8*)(xt_lo + d) = l;
}

// ---------------------------------------------------------------------------
// Kernel 1: projections, LDS double-buffered GEMM. Swizzle-aware fragment
// reads (kg ^ (c15&3)); staging addresses hoisted into register arrays.
// ---------------------------------------------------------------------------
__global__ __launch_bounds__(256) void proj_kernel(
    const unsigned short* __restrict__ xt_hi, const unsigned short* __restrict__ xt_lo,
    const unsigned short* __restrict__ wtt_hi, const unsigned short* __restrict__ wtt_lo,
    unsigned short* __restrict__ q_hi, unsigned short* __restrict__ q_lo,
    unsigned short* __restrict__ k_hi, unsigned short* __restrict__ k_lo,
    unsigned short* __restrict__ vtt)
{
    __shared__ __align__(16) unsigned short lds[2][12288];  // 48 KB
    int z = blockIdx.y;
    int mt = blockIdx.x;                       // 0..255
    int tid = threadIdx.x;
    int wave = tid >> 6, lane = tid & 63;
    int c15 = lane & 15, kg = lane >> 4;
    int sb = c15 & 3;                          // read-swizzle selector
    int mrow = wave >> 1, ncol = wave & 1;     // 2x2 wave grid

    const unsigned short* Ah0 = xt_hi + (size_t)mt * 32 * 2048;
    const unsigned short* Al0 = xt_lo + (size_t)mt * 32 * 2048;
    const unsigned short* Bh0 = wtt_hi + (size_t)z * 32 * 4096;
    const unsigned short* Bl0 = wtt_lo + (size_t)z * 32 * 4096;

    float4v acc[2][4];
#pragma unroll
    for (int i = 0; i < 2; i++)
#pragma unroll
        for (int j = 0; j < 4; j++) acc[i][j] = (float4v)0.0f;

    // hoisted staging descriptors: per-chunk global cursor, LDS offset
    // (buffer 0), per-ks stride. Computed once.
    const unsigned short* gcur[6];
    int lbo[6];
    int gstep[6];
    if (z < 2) {
#pragma unroll
        for (int i = 0; i < 6; i++) {
            int ch = wave * 6 + i;
            if (ch < 4)       { gcur[i] = Ah0 + ch * 512;        lbo[i] = ch * 512;               gstep[i] = 2048; }
            else if (ch < 8)  { gcur[i] = Al0 + (ch - 4) * 512;  lbo[i] = 2048 + (ch - 4) * 512;  gstep[i] = 2048; }
            else if (ch < 16) { gcur[i] = Bh0 + (ch - 8) * 512;  lbo[i] = 4096 + (ch - 8) * 512;  gstep[i] = 4096; }
            else              { gcur[i] = Bl0 + (ch - 16) * 512; lbo[i] = 8192 + (ch - 16) * 512; gstep[i] = 4096; }
        }
    } else {
#pragma unroll
        for (int i = 0; i < 3; i++) {
            int ch = wave * 3 + i;   // 0..11
            if (ch < 4) { gcur[i] = Ah0 + ch * 512;       lbo[i] = ch * 512;              gstep[i] = 2048; }
            else        { gcur[i] = Bh0 + (ch - 4) * 512; lbo[i] = 4096 + (ch - 4) * 512; gstep[i] = 4096; }
        }
    }
    int lo8 = lane * 8;

    auto stage = [&](int buf) {
        unsigned short* Lb = lds[0] + buf * 12288;
        if (z < 2) {
#pragma unroll
            for (int i = 0; i < 6; i++) {
                gll16(gcur[i] + lo8, Lb + lbo[i] + lo8);
                gcur[i] += gstep[i];
            }
        } else {
#pragma unroll
            for (int i = 0; i < 3; i++) {
                gll16(gcur[i] + lo8, Lb + lbo[i] + lo8);
                gcur[i] += gstep[i];
            }
        }
    };

    stage(0);

    for (int ks = 0; ks < 32; ks++) {
        __syncthreads();
        if (ks + 1 < 32) stage((ks + 1) & 1);
        const unsigned short* Lb = lds[ks & 1];

        short8 ah[2], al[2], bh[4], bl[4];
#pragma unroll
        for (int mi = 0; mi < 2; mi++) {
            int row = mrow * 32 + mi * 16 + c15;
            ah[mi] = *(const short8*)(Lb + row * 32 + (kg ^ sb) * 8);
        }
#pragma unroll
        for (int ni = 0; ni < 4; ni++) {
            int row = ncol * 64 + ni * 16 + c15;
            bh[ni] = *(const short8*)(Lb + 4096 + row * 32 + (kg ^ sb) * 8);
        }
        if (z < 2) {
#pragma unroll
            for (int mi = 0; mi < 2; mi++) {
                int row = mrow * 32 + mi * 16 + c15;
                al[mi] = *(const short8*)(Lb + 2048 + row * 32 + (kg ^ sb) * 8);
            }
#pragma unroll
            for (int ni = 0; ni < 4; ni++) {
                int row = ncol * 64 + ni * 16 + c15;
                bl[ni] = *(const short8*)(Lb + 8192 + row * 32 + (kg ^ sb) * 8);
            }
#pragma unroll
            for (int mi = 0; mi < 2; mi++)
#pragma unroll
                for (int ni = 0; ni < 4; ni++) {
                    acc[mi][ni] = MFMA16(ah[mi], bh[ni], acc[mi][ni]);
                    acc[mi][ni] = MFMA16(ah[mi], bl[ni], acc[mi][ni]);
                    acc[mi][ni] = MFMA16(al[mi], bh[ni], acc[mi][ni]);
                }
        } else {
#pragma unroll
            for (int mi = 0; mi < 2; mi++)
#pragma unroll
                for (int ni = 0; ni < 4; ni++)
                    acc[mi][ni] = MFMA16(ah[mi], bh[ni], acc[mi][ni]);
        }
    }

    if (z < 2) {
        unsigned short* oh = (z == 0) ? q_hi : k_hi;
        unsigned short* ol = (z == 0) ? q_lo : k_lo;
#pragma unroll
        for (int mi = 0; mi < 2; mi++) {
#pragma unroll
            for (int ni = 0; ni < 4; ni++) {
                int h = ncol * 64 + ni * 16 + c15;
#pragma unroll
                for (int r = 0; r < 4; r++) {
                    int t = mt * 64 + mrow * 32 + mi * 16 + kg * 4 + r;
                    float v = acc[mi][ni][r];
                    unsigned short hh = f2bf(v);
                    unsigned short ll = f2bf(v - bf2f(hh));
                    // swizzled: block (h>>3) of row t -> (h>>3) ^ (t&15)
                    size_t o = (size_t)t * Hn + (((h >> 3) ^ (t & 15)) << 3) + (h & 7);
                    oh[o] = hh;
                    ol[o] = ll;
                }
            }
        }
    } else {
        int b = mt >> 5;
#pragma unroll
        for (int mi = 0; mi < 2; mi++) {
            int t0 = (mt & 31) * 64 + mrow * 32 + mi * 16 + kg * 4;
            int sc = t0 >> 5, so = t0 & 31;
#pragma unroll
            for (int ni = 0; ni < 4; ni++) {
                int h = ncol * 64 + ni * 16 + c15;
                short4v pk;
#pragma unroll
                for (int r = 0; r < 4; r++) pk[r] = (short)f2bf(acc[mi][ni][r]);
                // swizzled: block (so>>3) of row h -> (so>>3) ^ ((h>>1)&3)
                int so2 = ((((so >> 3) ^ ((h >> 1) & 3))) << 3) | (so & 7);
                *(short4v*)(vtt + (((size_t)b * 64 + sc) * 128 + h) * 32 + so2) = pk;
            }
        }
    }
}

// ---------------------------------------------------------------------------
// Kernel 2: column softmax stats PARTIALS. t-loop of column tile sj split
// into nch = ((31-sj)>>2)+1 even chunks (<=8 iters). Single-buffer staging.
// R13: grid (B, 144) -> batch b = blockIdx.x pins all of batch b to XCD b.
// Chunk order (blockIdx.y) still heavy-first.
// ---------------------------------------------------------------------------
__global__ __launch_bounds__(256) void stats_part_kernel(
    const unsigned short* __restrict__ q_hi, const unsigned short* __restrict__ q_lo,
    const unsigned short* __restrict__ k_hi, const unsigned short* __restrict__ k_lo,
    float* __restrict__ m_part, float* __restrict__ l_part)
{
    __shared__ __align__(16) unsigned short lds[8192];  // 16 KB, single buffer
    int tid = threadIdx.x;
    int wave = tid >> 6, lane = tid & 63;
    int c15 = lane & 15, kg = lane >> 4;
    int b = blockIdx.x;                       // R13: batch on x -> XCD = b

    // map blockIdx.y -> (sj, ci); sj ascending = heavy first
    int rem = (int)blockIdx.y, sj, nch = 1;
    for (sj = 0; sj < 32; sj++) {
        nch = ((31 - sj) >> 2) + 1;
        if (rem < nch) break;
        rem -= nch;
    }
    int ci = rem;
    int c0 = 2 * sj;
    int len = 64 - c0;
    int cbase = len / nch, ext = len % nch;
    int cs = c0 + ci * cbase + (ci < ext ? ci : ext);
    int ce = cs + cbase + (ci < ext ? 1 : 0);

    int s_base = sj * 64 + wave * 16;

    // A fragments: wave's 16 k-rows; s&15 == c15 (s_base is x16-aligned)
    short8 a_h[4], a_l[4];
    {
        int s = s_base + c15;
        const unsigned short* kr = k_hi + ((size_t)(b * Tn + s)) * Hn;
        const unsigned short* krl = k_lo + ((size_t)(b * Tn + s)) * Hn;
#pragma unroll
        for (int st = 0; st < 4; st++) {
            int off = ((st * 4 + kg) ^ c15) * 8;
            a_h[st] = *(const short8*)(kr + off);
            a_l[st] = *(const short8*)(krl + off);
        }
    }
    float m[4], l[4];
#pragma unroll
    for (int r = 0; r < 4; r++) { m[r] = -3.0e38f; l[r] = 0.0f; }

    auto stage = [&](int c) {
        const unsigned short* Qh = q_hi + ((size_t)b * Tn + c * 32) * Hn;
        const unsigned short* Ql = q_lo + ((size_t)b * Tn + c * 32) * Hn;
        int lo8 = lane * 8;
#pragma unroll
        for (int i = 0; i < 4; i++) {
            int ch = wave * 4 + i;   // 0..15
            const unsigned short* g;
            unsigned short* ld;
            if (ch < 8) { g = Qh + ch * 512;       ld = lds + ch * 512; }
            else        { g = Ql + (ch - 8) * 512; ld = lds + 4096 + (ch - 8) * 512; }
            gll16(g + lo8, ld + lo8);
        }
    };

    for (int c = cs; c < ce; c++) {
        stage(c);
        __syncthreads();   // stage complete
#pragma unroll
        for (int half = 0; half < 2; half++) {
            int t16 = c * 32 + half * 16;
            int tl = half * 16 + c15;
            float4v a1 = (float4v)0.0f, a2 = (float4v)0.0f, a3 = (float4v)0.0f;
#pragma unroll
            for (int st = 0; st < 4; st++) {
                // swizzled block ((st*4+kg) ^ (t&15)); t&15 == c15
                int off = tl * 128 + ((st * 4 + kg) ^ c15) * 8;
                short8 bh = *(const short8*)(lds + off);
                short8 bl = *(const short8*)(lds + 4096 + off);
                a1 = MFMA16(a_h[st], bh, a1);
                a2 = MFMA16(a_h[st], bl, a2);
                a3 = MFMA16(a_l[st], bh, a3);
            }
            int t = t16 + c15;
#pragma unroll
            for (int r = 0; r < 4; r++) {
                float attv = (a1[r] + a2[r] + a3[r]) * SQRTH;
                int s_row = s_base + kg * 4 + r;
                bool valid = (t >= s_row);
                float cand = valid ? attv : -3.0e38f;
                float mn = fmaxf(m[r], cand);
                l[r] = l[r] * __expf(m[r] - mn) + (valid ? __expf(attv - mn) : 0.0f);
                m[r] = mn;
            }
        }
        __syncthreads();   // all reads done before next stage overwrites
    }
    // merge t-subsets across the 16 lanes sharing kg
#pragma unroll
    for (int mask = 1; mask < 16; mask <<= 1) {
#pragma unroll
        for (int r = 0; r < 4; r++) {
            float mo = __shfl_xor(m[r], mask);
            float lo2 = __shfl_xor(l[r], mask);
            float mn = fmaxf(m[r], mo);
            l[r] = l[r] * __expf(m[r] - mn) + lo2 * __expf(mo - mn);
            m[r] = mn;
        }
    }
    if (c15 == 0) {
#pragma unroll
        for (int r = 0; r < 4; r++) {
            int sl = wave * 16 + kg * 4 + r;           // 0..63 within tile
            size_t d = ((((size_t)b * 32 + sj) * 8 + ci) * 64) + sl;
            m_part[d] = m[r];
            l_part[d] = l[r];
        }
    }
}

// ---------------------------------------------------------------------------
// Kernel 2b: merge stats partials -> (m_st, il_st). 16384 columns.
// ---------------------------------------------------------------------------
__global__ __launch_bounds__(256) void stats_combine_kernel(
    const float* __restrict__ m_part, const float* __restrict__ l_part,
    float* __restrict__ m_st, float* __restrict__ il_st)
{
    int g = blockIdx.x * 256 + threadIdx.x;   // 0..16383
    int s = g & 2047, b = g >> 11;
    int sj = s >> 6, sl = s & 63;
    int nch = ((31 - sj) >> 2) + 1;
    size_t base = (((size_t)b * 32 + sj) * 8) * 64 + sl;
    float M = m_part[base];
    float L = l_part[base];
    for (int ci = 1; ci < nch; ci++) {
        float mi = m_part[base + (size_t)ci * 64];
        float li = l_part[base + (size_t)ci * 64];
        float mn = fmaxf(M, mi);
        L = L * __expf(M - mn) + li * __expf(mi - mn);
        M = mn;
    }
    m_st[(size_t)b * Tn + s] = M;
    il_st[(size_t)b * Tn + s] = 1.0f / L;
}

// ---------------------------------------------------------------------------
// Kernel 3: output PARTIALS. s-loop of row tile tj split into nch =
// (tj>>2)+1 even chunks (<=8 iters); fp32 partial tiles to workspace.
// Single-buffer staging. R13: grid (B, 144) -> XCD affinity by batch.
// ---------------------------------------------------------------------------
__global__ __launch_bounds__(256) void out_part_kernel(
    const unsigned short* __restrict__ q_hi, const unsigned short* __restrict__ q_lo,
    const unsigned short* __restrict__ k_hi, const unsigned short* __restrict__ k_lo,
    const unsigned short* __restrict__ vtt,
    const float* __restrict__ m_st, const float* __restrict__ il_st,
    float* __restrict__ part_out)
{
    __shared__ __align__(16) unsigned short lds[12288];      // 24 KB, single
    __shared__ __align__(16) unsigned short pbuf[4][16][40]; // 5 KB
    int tid = threadIdx.x;
    int wave = tid >> 6, lane = tid & 63;
    int c15 = lane & 15, kg = lane >> 4;
    int b = blockIdx.x;                       // R13: batch on x -> XCD = b

    // map blockIdx.y -> (tj, ci); tj descending = heavy first
    int rem = (int)blockIdx.y, tj, nch = 1;
    for (tj = 31; tj >= 0; tj--) {
        nch = (tj >> 2) + 1;
        if (rem < nch) break;
        rem -= nch;
    }
    int ci = rem;
    int len = 2 * tj + 2;
    int cbase = len / nch, ext = len % nch;
    int cs = ci * cbase + (ci < ext ? ci : ext);
    int ce = cs + cbase + (ci < ext ? 1 : 0);

    int t_base = tj * 64 + wave * 16;

    // A fragments: wave's 16 q-rows; t&15 == c15
    short8 qa_h[4], qa_l[4];
    {
        int t = t_base + c15;
        const unsigned short* qr = q_hi + ((size_t)(b * Tn + t)) * Hn;
        const unsigned short* qrl = q_lo + ((size_t)(b * Tn + t)) * Hn;
#pragma unroll
        for (int st = 0; st < 4; st++) {
            int off = ((st * 4 + kg) ^ c15) * 8;
            qa_h[st] = *(const short8*)(qr + off);
            qa_l[st] = *(const short8*)(qrl + off);
        }
    }
    float4v oacc[8];
#pragma unroll
    for (int i = 0; i < 8; i++) oacc[i] = (float4v)0.0f;

    auto stage = [&](int c) {
        const unsigned short* Kh = k_hi + ((size_t)b * Tn + c * 32) * Hn;
        const unsigned short* Kl = k_lo + ((size_t)b * Tn + c * 32) * Hn;
        const unsigned short* Vv = vtt + ((size_t)b * 64 + c) * (128 * 32);
        int lo8 = lane * 8;
#pragma unroll
        for (int i = 0; i < 6; i++) {
            int ch = wave * 6 + i;   // 0..23
            const unsigned short* g;
            unsigned short* ld;
            if (ch < 8)       { g = Kh + ch * 512;        ld = lds + ch * 512; }
            else if (ch < 16) { g = Kl + (ch - 8) * 512;  ld = lds + 4096 + (ch - 8) * 512; }
            else              { g = Vv + (ch - 16) * 512; ld = lds + 8192 + (ch - 16) * 512; }
            gll16(g + lo8, ld + lo8);
        }
    };

    for (int c = cs; c < ce; c++) {
        stage(c);
        __syncthreads();   // stage complete
#pragma unroll
        for (int half = 0; half < 2; half++) {
            int s16 = c * 32 + half * 16;
            int sl = half * 16 + c15;
            float4v a1 = (float4v)0.0f, a2 = (float4v)0.0f, a3 = (float4v)0.0f;
#pragma unroll
            for (int st = 0; st < 4; st++) {
                // swizzled block ((st*4+kg) ^ (s&15)); s&15 == c15
                int off = sl * 128 + ((st * 4 + kg) ^ c15) * 8;
                short8 bh = *(const short8*)(lds + off);
                short8 bl = *(const short8*)(lds + 4096 + off);
                a1 = MFMA16(qa_h[st], bh, a1);
                a2 = MFMA16(qa_h[st], bl, a2);
                a3 = MFMA16(qa_l[st], bh, a3);
            }
            float msv = m_st[b * Tn + s16 + c15];
            float ilv = il_st[b * Tn + s16 + c15];
#pragma unroll
            for (int r = 0; r < 4; r++) {
                int t = t_base + kg * 4 + r;
                float attv = (a1[r] + a2[r] + a3[r]) * SQRTH;
                // clamp: att <= column max for true data (ULP-exact safety)
                float earg = fminf(attv - msv, 0.0f);
                float p = (t >= s16 + c15) ? __expf(earg) * ilv : 0.0f;
                pbuf[wave][kg * 4 + r][c15 + half * 16] = f2bf(p);
            }
        }
        // C-layout -> A-layout via LDS (wave-internal, DS pipe in-order)
        short8 pa = *(const short8*)&pbuf[wave][c15][kg * 8];
#pragma unroll
        for (int nt = 0; nt < 8; nt++) {
            // vtt row h = nt*16+c15; swizzled block kg ^ ((h>>1)&3),
            // (h>>1)&3 == (c15>>1)&3 since nt*16 is a multiple of 8 in h>>1
            int voff = (nt * 16 + c15) * 32 + ((kg ^ ((c15 >> 1) & 3)) * 8);
            short8 vb = *(const short8*)(lds + 8192 + voff);
            oacc[nt] = MFMA16(pa, vb, oacc[nt]);
        }
        __syncthreads();   // all reads done before next stage overwrites
    }
    // partial tile store: part[b][tj][ci][t_local 64][h 128]
    float* po = part_out + ((((size_t)b * 32 + tj) * 8 + ci) * 64) * 128;
#pragma unroll
    for (int nt = 0; nt < 8; nt++) {
        int h = nt * 16 + c15;
#pragma unroll
        for (int r = 0; r < 4; r++) {
            int tl = wave * 16 + kg * 4 + r;
            po[(size_t)tl * 128 + h] = oacc[nt][r];
        }
    }
}

// ---------------------------------------------------------------------------
// Kernel 3b: sum output partials -> out. 2M floats, float4 loads/stores.
// ---------------------------------------------------------------------------
__global__ __launch_bounds__(256) void out_combine_kernel(
    const float* __restrict__ part_out, float* __restrict__ out)
{
    int g = blockIdx.x * 256 + threadIdx.x;   // 0..524287 (float4 units)
    int h4 = g & 31;
    int t = (g >> 5) & 2047;
    int b = g >> 16;
    int tj = t >> 6, tl = t & 63;
    int nch = (tj >> 2) + 1;
    const float4v* p = (const float4v*)(part_out
        + ((((size_t)b * 32 + tj) * 8) * 64 + tl) * 128) + h4;
    float4v acc = p[0];
    for (int ci = 1; ci < nch; ci++) acc += p[(size_t)ci * 2048];  // slot = 8192 floats
    *((float4v*)(out + ((size_t)b * Tn + t) * Hn) + h4) = acc;
}

// ---------------------------------------------------------------------------
extern "C" void kernel_launch(void* const* d_in, const int* in_sizes, int n_in,
                              void* d_out, int out_size, void* d_ws, size_t ws_size,
                              hipStream_t stream)
{
    (void)in_sizes; (void)n_in; (void)out_size; (void)ws_size;
    const float* x  = (const float*)d_in[0];
    const float* Wk = (const float*)d_in[1];
    const float* Wq = (const float*)d_in[2];
    const float* Wv = (const float*)d_in[3];
    float* out = (float*)d_out;

    const size_t NQ = (size_t)Bn * Tn * Hn;        // 2,097,152
    const size_t NX = (size_t)Bn * Tn * En;        // 16,777,216
    unsigned short* q_hi = (unsigned short*)d_ws;
    unsigned short* q_lo = q_hi + NQ;
    unsigned short* k_hi = q_lo + NQ;
    unsigned short* k_lo = k_hi + NQ;
    unsigned short* vtt  = k_lo + NQ;
    unsigned short* xt_hi = vtt + NQ;
    unsigned short* xt_lo = xt_hi + NX;
    unsigned short* wtt_hi = xt_lo + NX;
    unsigned short* wtt_lo = wtt_hi + (size_t)3 * Hn * En;
    float* m_st  = (float*)(wtt_lo + (size_t)3 * Hn * En);
    float* il_st = m_st + (size_t)Bn * Tn;
    // total ws use: ~89.4 MB — identical extent to the validated R7 layout

    // Dead-after-proj aliases:
    //  part_out = xt region: 8*32*8*64*128 fp32 = 67.1 MB == sizeof(xt_hi+xt_lo)
    //  m_part/l_part = wtt region: 8*32*8*64 fp32 = 512 KB each (<= 768 KB)
    float* part_out = (float*)xt_hi;
    float* m_part   = (float*)wtt_hi;
    float* l_part   = (float*)wtt_lo;

    wtrans_kernel<<<dim3(192), 256, 0, stream>>>(Wq, Wk, Wv, wtt_hi, wtt_lo);
    xconv_kernel<<<dim3(8192), 256, 0, stream>>>(x, xt_hi, xt_lo);
    proj_kernel<<<dim3(256, 3), 256, 0, stream>>>(xt_hi, xt_lo, wtt_hi, wtt_lo,
                                                  q_hi, q_lo, k_hi, k_lo, vtt);
    stats_part_kernel<<<dim3(Bn, 144), 256, 0, stream>>>(q_hi, q_lo, k_hi, k_lo,
                                                         m_part, l_part);
    stats_combine_kernel<<<dim3(64), 256, 0, stream>>>(m_part, l_part, m_st, il_st);
    out_part_kernel<<<dim3(Bn, 144), 256, 0, stream>>>(q_hi, q_lo, k_hi, k_lo, vtt,
                                                       m_st, il_st, part_out);
    out_combine_kernel<<<dim3(2048), 256, 0, stream>>>(part_out, out);
}